// Round 7
// baseline (324.933 us; speedup 1.0000x reference)
//
#include <hip/hip_runtime.h>
#include <math.h>

#define NB   128
#define CF   1024
#define RR   256
#define NA   312
#define DV   300
#define M2   320
#define MT   640
#define NKC  32

typedef _Float16 half8  __attribute__((ext_vector_type(8)));
typedef float float16v  __attribute__((ext_vector_type(16)));

// ---- K1: merged prep (sumsq + f16 transpose) and q (Q projection) ----
// blocks 0..511: prep; blocks 512..831: q
__global__ void k_pre(const float* __restrict__ img, float* __restrict__ invg,
                      _Float16* __restrict__ avT,
                      const float* __restrict__ V, const float* __restrict__ W1,
                      const float* __restrict__ W2, _Float16* __restrict__ Qb) {
    int t = threadIdx.x;
    __shared__ __align__(16) char sm[64 * 65 * 4];
    __shared__ float inv8[8];

    if (blockIdx.x < 512) {
        // ---------- prep: one block per (r-chunk rc, batch b) ----------
        int rc = blockIdx.x & 3, b = blockIdx.x >> 2;
        int r0 = rc * 64;
        _Float16 (*tile)[65] = (_Float16 (*)[65])sm;
        float    (*ssb)[65]  = (float    (*)[65])sm;
        int fl = t >> 2, cg = t & 3;
        int rl = t >> 2, g  = t & 3;
        float ss[16];
        #pragma unroll
        for (int j = 0; j < 16; ++j) ss[j] = 0.f;

        for (int cc = 0; cc < 16; ++cc) {
            int f0 = cc * 64;
            const float4* p4 = (const float4*)(img + ((size_t)(b * CF + f0 + fl)) * RR + r0 + cg * 16);
            float4 v0 = p4[0], v1 = p4[1], v2 = p4[2], v3 = p4[3];
            __syncthreads();
            float xs[16] = {v0.x, v0.y, v0.z, v0.w, v1.x, v1.y, v1.z, v1.w,
                            v2.x, v2.y, v2.z, v2.w, v3.x, v3.y, v3.z, v3.w};
            #pragma unroll
            for (int j = 0; j < 16; ++j) {
                ss[j] += xs[j] * xs[j];
                tile[fl][cg * 16 + j] = (_Float16)xs[j];
            }
            __syncthreads();
            int kc  = (f0 >> 5) + (g >> 1);
            int kkb = (g & 1) * 16;
            half8 o0, o1;
            #pragma unroll
            for (int j = 0; j < 8; ++j) o0[j] = tile[g * 16 + j][rl];
            #pragma unroll
            for (int j = 0; j < 8; ++j) o1[j] = tile[g * 16 + 8 + j][rl];
            _Float16* q = avT + (((size_t)(b * NKC + kc) * RR + r0 + rl) * 32 + kkb);
            *(half8*)q       = o0;
            *(half8*)(q + 8) = o1;
        }
        __syncthreads();
        #pragma unroll
        for (int j = 0; j < 16; ++j) ssb[fl][cg * 16 + j] = ss[j];
        __syncthreads();
        if (t < 64) {
            float tot = 0.f;
            for (int f2 = 0; f2 < 64; ++f2) tot += ssb[f2][t];
            invg[b * RR + r0 + t] = 1.f / fmaxf(sqrtf(tot), 1e-12f);
        }
    } else {
        // ---------- q: Q = [l2norm(V)@W1 ; pad ; l2norm(V)@W2 ; pad] ----------
        int qi = blockIdx.x - 512;       // 0..319
        int ib = qi % 80;
        int f  = (qi / 80) * 256 + t;
        int i0 = ib * 8;
        float acc[8] = {0,0,0,0,0,0,0,0};
        bool zero = (ib == 39 || ib == 79);
        int v0 = (ib < 40) ? i0 : i0 - M2;
        if (!zero) {
            int row = t >> 5, l32 = t & 31;
            float s = 0.f;
            for (int v = l32; v < DV; v += 32) { float x = V[(v0 + row) * DV + v]; s += x * x; }
            #pragma unroll
            for (int o = 16; o; o >>= 1) s += __shfl_xor(s, o, 32);
            if (l32 == 0) inv8[row] = 1.f / fmaxf(sqrtf(s), 1e-12f);
            __syncthreads();
            const float* W = (ib < 40) ? W1 : W2;
            for (int v = 0; v < DV; ++v) {
                float wv = W[(size_t)v * CF + f];
                #pragma unroll
                for (int ii = 0; ii < 8; ++ii) acc[ii] += V[(v0 + ii) * DV + v] * wv;
            }
            #pragma unroll
            for (int ii = 0; ii < 8; ++ii) acc[ii] *= inv8[ii];
        }
        #pragma unroll
        for (int ii = 0; ii < 8; ++ii)
            Qb[((size_t)(f >> 5) * MT + (i0 + ii)) * 32 + (f & 31)] = (_Float16)acc[ii];
    }
}

// ---- K2: batched GEMM, M=128 x N=256, VGPR-mediated staging (no LDS DMA) ----
// Barriers only wait lgkm (ds_writes); global loads float across barriers with
// compiler-generated fine-grained vmcnt(N) — escapes the vmcnt(0) drain.
__launch_bounds__(256, 2)
__global__ void k_gemm(const _Float16* __restrict__ Qb, const _Float16* __restrict__ avT,
                       const float* __restrict__ invg, float* __restrict__ out) {
    int lin  = blockIdx.x;
    int xcd  = lin & 7;
    int slot = lin >> 3;
    int bq   = slot / 5;
    int t2   = slot - bq * 5;     // 0..4
    int b    = bq * 8 + xcd;

    int tid = threadIdx.x;
    int lane = tid & 63, w = tid >> 6;
    int nl = lane & 31, kh = lane >> 5;

    // LDS: A0@0 (8K), A1@8K (8K), B0@16K (16K), B1@32K (16K) = 48 KB
    __shared__ __align__(16) char smem[49152];
    _Float16* A0 = (_Float16*)smem;
    _Float16* A1 = (_Float16*)(smem + 8192);
    _Float16* B0 = (_Float16*)(smem + 16384);
    _Float16* B1 = (_Float16*)(smem + 32768);
    // epilogue overlays (inside dead A region, used only after k-loop):
    float* mred = (float*)smem;            // [64][4]
    float* mg   = (float*)(smem + 1024);   // [64]
    float* sred = (float*)(smem + 1280);   // [64][4]
    float* dred = (float*)(smem + 2304);   // [64][4]

    float16v acc[4][2];   // [rf: Q1a,Q1b,Q2a,Q2b][cb]
    #pragma unroll
    for (int i = 0; i < 4; ++i)
        #pragma unroll
        for (int j = 0; j < 2; ++j)
            #pragma unroll
            for (int gi = 0; gi < 16; ++gi) acc[i][j][gi] = 0.f;

    // staging thread->element maps (same addresses the DMA version used)
    int arow  = tid & 127;
    int akb0  = tid >> 7;                               // 0/1 (kb and kb+2)
    int grow  = (arow < 64) ? (t2 * 64 + arow) : (M2 + t2 * 64 + (arow - 64));
    size_t a_src0 = (size_t)grow * 32 + akb0 * 8;       // + kc*MT*32
    size_t a_dst0 = ((size_t)akb0 * 128 + arow) * 8;    // A LDS [kb][row][8]
    size_t b_src0 = (size_t)tid * 32;                   // + kc*RR*32 + rd*8
    size_t b_dst0 = (size_t)tid * 8;                    // + rd*2048
    const _Float16* bpanel = avT + (size_t)b * NKC * RR * 32;

    half8 aR0[2], bR0[4], aR1[2], bR1[4];

    #define STAGE_LOAD(kc_, Av, Bv) do {                                        \
        int kcl = ((kc_) < NKC) ? (kc_) : (NKC - 1);                            \
        const _Float16* as = Qb + (size_t)kcl * MT * 32;                        \
        (Av)[0] = *(const half8*)(as + a_src0);                                 \
        (Av)[1] = *(const half8*)(as + a_src0 + 16);                            \
        const _Float16* bs = bpanel + (size_t)kcl * RR * 32;                    \
        (Bv)[0] = *(const half8*)(bs + b_src0 + 0 * 8);                         \
        (Bv)[1] = *(const half8*)(bs + b_src0 + 1 * 8);                         \
        (Bv)[2] = *(const half8*)(bs + b_src0 + 2 * 8);                         \
        (Bv)[3] = *(const half8*)(bs + b_src0 + 3 * 8);                         \
    } while (0)

    #define STAGE_WRITE(Av, Bv, Ad, Bd) do {                                    \
        *(half8*)((Ad) + a_dst0)        = (Av)[0];                              \
        *(half8*)((Ad) + a_dst0 + 2048) = (Av)[1];                              \
        *(half8*)((Bd) + b_dst0 + 0 * 2048) = (Bv)[0];                          \
        *(half8*)((Bd) + b_dst0 + 1 * 2048) = (Bv)[1];                          \
        *(half8*)((Bd) + b_dst0 + 2 * 2048) = (Bv)[2];                          \
        *(half8*)((Bd) + b_dst0 + 3 * 2048) = (Bv)[3];                          \
    } while (0)

    #define COMPUTE(Al, Bl) do {                                                \
        _Pragma("unroll")                                                       \
        for (int ks = 0; ks < 2; ++ks) {                                        \
            int kb = ks * 2 + kh;                                               \
            half8 b0f = *(const half8*)((Bl) + ((size_t)kb * 256 + w * 64 + nl) * 8);       \
            half8 b1f = *(const half8*)((Bl) + ((size_t)kb * 256 + w * 64 + 32 + nl) * 8);  \
            _Pragma("unroll")                                                   \
            for (int rf = 0; rf < 4; ++rf) {                                    \
                half8 af = *(const half8*)((Al) + ((size_t)kb * 128 + rf * 32 + nl) * 8);   \
                acc[rf][0] = __builtin_amdgcn_mfma_f32_32x32x16_f16(af, b0f, acc[rf][0], 0, 0, 0); \
                acc[rf][1] = __builtin_amdgcn_mfma_f32_32x32x16_f16(af, b1f, acc[rf][1], 0, 0, 0); \
            }                                                                   \
        }                                                                       \
    } while (0)

    STAGE_LOAD(0, aR0, bR0);
    STAGE_LOAD(1, aR1, bR1);
    STAGE_WRITE(aR0, bR0, A0, B0);

    for (int kc = 0; kc < NKC; kc += 2) {
        __syncthreads();                       // buf0(kc) visible; buf1 readers done
        STAGE_WRITE(aR1, bR1, A1, B1);         // write kc+1 while computing buf0
        STAGE_LOAD(kc + 2, aR0, bR0);          // issue loads for kc+2 (clamped)
        COMPUTE(A0, B0);
        __syncthreads();                       // buf1(kc+1) visible; buf0 readers done
        if (kc + 2 < NKC) STAGE_WRITE(aR0, bR0, A0, B0);
        STAGE_LOAD(kc + 3, aR1, bR1);          // loads for kc+3 (clamped)
        COMPUTE(A1, B1);
    }
    __syncthreads();                           // overlay safe
    #undef STAGE_LOAD
    #undef STAGE_WRITE
    #undef COMPUTE

    // ---- epilogue: scale by inv[col], softmax over r (rf=p logits, rf=p+2 values) ----
    float iv0 = invg[b * RR + w * 64 + nl];
    float iv1 = invg[b * RR + w * 64 + 32 + nl];
    #pragma unroll
    for (int rf = 0; rf < 4; ++rf)
        #pragma unroll
        for (int gi = 0; gi < 16; ++gi) {
            acc[rf][0][gi] *= iv0;
            acc[rf][1][gi] *= iv1;
        }

    float mx[2][16];
    #pragma unroll
    for (int p = 0; p < 2; ++p)
        #pragma unroll
        for (int gi = 0; gi < 16; ++gi)
            mx[p][gi] = fmaxf(acc[p][0][gi], acc[p][1][gi]);
    #pragma unroll
    for (int off = 1; off <= 16; off <<= 1)
        #pragma unroll
        for (int p = 0; p < 2; ++p)
            #pragma unroll
            for (int gi = 0; gi < 16; ++gi)
                mx[p][gi] = fmaxf(mx[p][gi], __shfl_xor(mx[p][gi], off, 64));
    if (nl == 0) {
        #pragma unroll
        for (int p = 0; p < 2; ++p)
            #pragma unroll
            for (int gi = 0; gi < 16; ++gi) {
                int row = (gi & 3) + 8 * (gi >> 2) + 4 * kh;
                mred[(p * 32 + row) * 4 + w] = mx[p][gi];
            }
    }
    __syncthreads();
    if (tid < 64)
        mg[tid] = fmaxf(fmaxf(mred[tid * 4], mred[tid * 4 + 1]),
                        fmaxf(mred[tid * 4 + 2], mred[tid * 4 + 3]));
    __syncthreads();
    float sp[2][16], dp[2][16];
    #pragma unroll
    for (int p = 0; p < 2; ++p)
        #pragma unroll
        for (int gi = 0; gi < 16; ++gi) {
            int row = (gi & 3) + 8 * (gi >> 2) + 4 * kh;
            float m  = mg[p * 32 + row];
            float e0 = __expf(acc[p][0][gi] - m);
            float e1 = __expf(acc[p][1][gi] - m);
            sp[p][gi] = e0 + e1;
            dp[p][gi] = e0 * acc[p + 2][0][gi] + e1 * acc[p + 2][1][gi];
        }
    #pragma unroll
    for (int off = 1; off <= 16; off <<= 1)
        #pragma unroll
        for (int p = 0; p < 2; ++p)
            #pragma unroll
            for (int gi = 0; gi < 16; ++gi) {
                sp[p][gi] += __shfl_xor(sp[p][gi], off, 64);
                dp[p][gi] += __shfl_xor(dp[p][gi], off, 64);
            }
    if (nl == 0) {
        #pragma unroll
        for (int p = 0; p < 2; ++p)
            #pragma unroll
            for (int gi = 0; gi < 16; ++gi) {
                int row = (gi & 3) + 8 * (gi >> 2) + 4 * kh;
                sred[(p * 32 + row) * 4 + w] = sp[p][gi];
                dred[(p * 32 + row) * 4 + w] = dp[p][gi];
            }
    }
    __syncthreads();
    if (tid < 64) {
        float s = sred[tid * 4] + sred[tid * 4 + 1] + sred[tid * 4 + 2] + sred[tid * 4 + 3];
        float d = dred[tid * 4] + dred[tid * 4 + 1] + dred[tid * 4 + 2] + dred[tid * 4 + 3];
        int ig = t2 * 64 + tid;
        if (ig < NA) out[b * NA + ig] = d / s;
    }
}

// ---- launcher ----
extern "C" void kernel_launch(void* const* d_in, const int* in_sizes, int n_in,
                              void* d_out, int out_size, void* d_ws, size_t ws_size,
                              hipStream_t stream) {
    const float* img = (const float*)d_in[0];
    const float* V   = (const float*)d_in[1];
    const float* W1  = (const float*)d_in[2];
    const float* W2  = (const float*)d_in[3];
    float* out = (float*)d_out;

    char* ws = (char*)d_ws;
    size_t off = 0;
    float*    invg = (float*)(ws + off);    off += (size_t)NB * RR * 4;
    _Float16* avT  = (_Float16*)(ws + off); off += (size_t)NB * CF * RR * 2;
    _Float16* Qb   = (_Float16*)(ws + off); off += (size_t)NKC * MT * 32 * 2;

    k_pre<<<dim3(832), 256, 0, stream>>>(img, invg, avT, V, W1, W2, Qb);
    k_gemm<<<dim3(640), 256, 0, stream>>>(Qb, avT, invg, out);
}

// Round 8
// 301.360 us; speedup vs baseline: 1.0782x; 1.0782x over previous
//
#include <hip/hip_runtime.h>
#include <math.h>

#define NB   128
#define CF   1024
#define RR   256
#define NA   312
#define DV   300
#define M2   320
#define MT   640
#define NKC  32

typedef _Float16 half8  __attribute__((ext_vector_type(8)));
typedef float float16v  __attribute__((ext_vector_type(16)));

// ---- K1: fused sumsq + raw f16 transpose; one block per (r-chunk, b) ----
__global__ void k_prep(const float* __restrict__ img, float* __restrict__ invg,
                       _Float16* __restrict__ avT) {
    int rc = blockIdx.x, b = blockIdx.y;
    int r0 = rc * 64;
    int t = threadIdx.x;
    __shared__ __align__(16) char sm[64 * 65 * 4];
    _Float16 (*tile)[65] = (_Float16 (*)[65])sm;
    float    (*ssb)[65]  = (float    (*)[65])sm;
    int fl = t >> 2, cg = t & 3;
    int rl = t >> 2, g  = t & 3;
    float ss[16];
    #pragma unroll
    for (int j = 0; j < 16; ++j) ss[j] = 0.f;

    for (int cc = 0; cc < 16; ++cc) {
        int f0 = cc * 64;
        const float4* p4 = (const float4*)(img + ((size_t)(b * CF + f0 + fl)) * RR + r0 + cg * 16);
        float4 v0 = p4[0], v1 = p4[1], v2 = p4[2], v3 = p4[3];
        __syncthreads();
        float xs[16] = {v0.x, v0.y, v0.z, v0.w, v1.x, v1.y, v1.z, v1.w,
                        v2.x, v2.y, v2.z, v2.w, v3.x, v3.y, v3.z, v3.w};
        #pragma unroll
        for (int j = 0; j < 16; ++j) {
            ss[j] += xs[j] * xs[j];
            tile[fl][cg * 16 + j] = (_Float16)xs[j];
        }
        __syncthreads();
        int kc  = (f0 >> 5) + (g >> 1);
        int kkb = (g & 1) * 16;
        half8 o0, o1;
        #pragma unroll
        for (int j = 0; j < 8; ++j) o0[j] = tile[g * 16 + j][rl];
        #pragma unroll
        for (int j = 0; j < 8; ++j) o1[j] = tile[g * 16 + 8 + j][rl];
        _Float16* q = avT + (((size_t)(b * NKC + kc) * RR + r0 + rl) * 32 + kkb);
        *(half8*)q       = o0;
        *(half8*)(q + 8) = o1;
    }
    __syncthreads();
    #pragma unroll
    for (int j = 0; j < 16; ++j) ssb[fl][cg * 16 + j] = ss[j];
    __syncthreads();
    if (t < 64) {
        float tot = 0.f;
        for (int f2 = 0; f2 < 64; ++f2) tot += ssb[f2][t];
        invg[b * RR + r0 + t] = 1.f / fmaxf(sqrtf(tot), 1e-12f);
    }
}

// ---- K2: Q projection, 4 rows/block, v-loop unrolled 4x for MLP ----
// blockIdx.x: 0..159 (ib; <80 -> Q1 rows, >=80 -> Q2 rows), blockIdx.y: f-chunk
__global__ void k_q(const float* __restrict__ V, const float* __restrict__ W1,
                    const float* __restrict__ W2, _Float16* __restrict__ Qb) {
    int ib = blockIdx.x;
    int f  = blockIdx.y * 256 + threadIdx.x;
    int t  = threadIdx.x;
    bool isQ2 = ib >= 80;
    int i0l = (ib - (isQ2 ? 80 : 0)) * 4;     // logical V row base
    int i0g = (isQ2 ? M2 : 0) + i0l;          // padded Q row base
    __shared__ float inv4[4];
    float acc[4] = {0, 0, 0, 0};
    bool zero = (i0l >= NA);                  // pad rows 312..319 (block-uniform)
    if (!zero) {
        int row = t >> 6, l64 = t & 63;
        float s = 0.f;
        for (int v = l64; v < DV; v += 64) { float x = V[(i0l + row) * DV + v]; s += x * x; }
        #pragma unroll
        for (int o = 32; o; o >>= 1) s += __shfl_xor(s, o, 64);
        if (l64 == 0) inv4[row] = 1.f / fmaxf(sqrtf(s), 1e-12f);
        __syncthreads();
        const float* W = isQ2 ? W2 : W1;
        for (int v = 0; v < DV; v += 4) {     // DV=300 divisible by 4
            float w0 = W[(size_t)(v + 0) * CF + f];
            float w1 = W[(size_t)(v + 1) * CF + f];
            float w2 = W[(size_t)(v + 2) * CF + f];
            float w3 = W[(size_t)(v + 3) * CF + f];
            #pragma unroll
            for (int ii = 0; ii < 4; ++ii) {
                const float* Vr = V + (size_t)(i0l + ii) * DV + v;
                acc[ii] += Vr[0] * w0 + Vr[1] * w1 + Vr[2] * w2 + Vr[3] * w3;
            }
        }
        #pragma unroll
        for (int ii = 0; ii < 4; ++ii) acc[ii] *= inv4[ii];
    }
    #pragma unroll
    for (int ii = 0; ii < 4; ++ii)
        Qb[((size_t)(f >> 5) * MT + (i0g + ii)) * 32 + (f & 31)] = (_Float16)acc[ii];
}

// ---- K3: batched GEMM, M=128 x N=256, VGPR-mediated staging ----
__launch_bounds__(256, 2)
__global__ void k_gemm(const _Float16* __restrict__ Qb, const _Float16* __restrict__ avT,
                       const float* __restrict__ invg, float* __restrict__ out) {
    int lin  = blockIdx.x;
    int xcd  = lin & 7;
    int slot = lin >> 3;
    int bq   = slot / 5;
    int t2   = slot - bq * 5;
    int b    = bq * 8 + xcd;

    int tid = threadIdx.x;
    int lane = tid & 63, w = tid >> 6;
    int nl = lane & 31, kh = lane >> 5;

    __shared__ __align__(16) char smem[49152];
    _Float16* A0 = (_Float16*)smem;
    _Float16* A1 = (_Float16*)(smem + 8192);
    _Float16* B0 = (_Float16*)(smem + 16384);
    _Float16* B1 = (_Float16*)(smem + 32768);
    float* mred = (float*)smem;
    float* mg   = (float*)(smem + 1024);
    float* sred = (float*)(smem + 1280);
    float* dred = (float*)(smem + 2304);

    float16v acc[4][2];
    #pragma unroll
    for (int i = 0; i < 4; ++i)
        #pragma unroll
        for (int j = 0; j < 2; ++j)
            #pragma unroll
            for (int gi = 0; gi < 16; ++gi) acc[i][j][gi] = 0.f;

    int arow  = tid & 127;
    int akb0  = tid >> 7;
    int grow  = (arow < 64) ? (t2 * 64 + arow) : (M2 + t2 * 64 + (arow - 64));
    size_t a_src0 = (size_t)grow * 32 + akb0 * 8;
    size_t a_dst0 = ((size_t)akb0 * 128 + arow) * 8;
    size_t b_src0 = (size_t)tid * 32;
    size_t b_dst0 = (size_t)tid * 8;
    const _Float16* bpanel = avT + (size_t)b * NKC * RR * 32;

    half8 aR0[2], bR0[4], aR1[2], bR1[4];

    #define STAGE_LOAD(kc_, Av, Bv) do {                                        \
        int kcl = ((kc_) < NKC) ? (kc_) : (NKC - 1);                            \
        const _Float16* as = Qb + (size_t)kcl * MT * 32;                        \
        (Av)[0] = *(const half8*)(as + a_src0);                                 \
        (Av)[1] = *(const half8*)(as + a_src0 + 16);                            \
        const _Float16* bs = bpanel + (size_t)kcl * RR * 32;                    \
        (Bv)[0] = *(const half8*)(bs + b_src0 + 0 * 8);                         \
        (Bv)[1] = *(const half8*)(bs + b_src0 + 1 * 8);                         \
        (Bv)[2] = *(const half8*)(bs + b_src0 + 2 * 8);                         \
        (Bv)[3] = *(const half8*)(bs + b_src0 + 3 * 8);                         \
    } while (0)

    #define STAGE_WRITE(Av, Bv, Ad, Bd) do {                                    \
        *(half8*)((Ad) + a_dst0)        = (Av)[0];                              \
        *(half8*)((Ad) + a_dst0 + 2048) = (Av)[1];                              \
        *(half8*)((Bd) + b_dst0 + 0 * 2048) = (Bv)[0];                          \
        *(half8*)((Bd) + b_dst0 + 1 * 2048) = (Bv)[1];                          \
        *(half8*)((Bd) + b_dst0 + 2 * 2048) = (Bv)[2];                          \
        *(half8*)((Bd) + b_dst0 + 3 * 2048) = (Bv)[3];                          \
    } while (0)

    #define COMPUTE(Al, Bl) do {                                                \
        _Pragma("unroll")                                                       \
        for (int ks = 0; ks < 2; ++ks) {                                        \
            int kb = ks * 2 + kh;                                               \
            half8 b0f = *(const half8*)((Bl) + ((size_t)kb * 256 + w * 64 + nl) * 8);       \
            half8 b1f = *(const half8*)((Bl) + ((size_t)kb * 256 + w * 64 + 32 + nl) * 8);  \
            _Pragma("unroll")                                                   \
            for (int rf = 0; rf < 4; ++rf) {                                    \
                half8 af = *(const half8*)((Al) + ((size_t)kb * 128 + rf * 32 + nl) * 8);   \
                acc[rf][0] = __builtin_amdgcn_mfma_f32_32x32x16_f16(af, b0f, acc[rf][0], 0, 0, 0); \
                acc[rf][1] = __builtin_amdgcn_mfma_f32_32x32x16_f16(af, b1f, acc[rf][1], 0, 0, 0); \
            }                                                                   \
        }                                                                       \
    } while (0)

    STAGE_LOAD(0, aR0, bR0);
    STAGE_LOAD(1, aR1, bR1);
    STAGE_WRITE(aR0, bR0, A0, B0);

    for (int kc = 0; kc < NKC; kc += 2) {
        __syncthreads();
        STAGE_WRITE(aR1, bR1, A1, B1);
        STAGE_LOAD(kc + 2, aR0, bR0);
        COMPUTE(A0, B0);
        __syncthreads();
        if (kc + 2 < NKC) STAGE_WRITE(aR0, bR0, A0, B0);
        STAGE_LOAD(kc + 3, aR1, bR1);
        COMPUTE(A1, B1);
    }
    __syncthreads();
    #undef STAGE_LOAD
    #undef STAGE_WRITE
    #undef COMPUTE

    float iv0 = invg[b * RR + w * 64 + nl];
    float iv1 = invg[b * RR + w * 64 + 32 + nl];
    #pragma unroll
    for (int rf = 0; rf < 4; ++rf)
        #pragma unroll
        for (int gi = 0; gi < 16; ++gi) {
            acc[rf][0][gi] *= iv0;
            acc[rf][1][gi] *= iv1;
        }

    float mx[2][16];
    #pragma unroll
    for (int p = 0; p < 2; ++p)
        #pragma unroll
        for (int gi = 0; gi < 16; ++gi)
            mx[p][gi] = fmaxf(acc[p][0][gi], acc[p][1][gi]);
    #pragma unroll
    for (int off = 1; off <= 16; off <<= 1)
        #pragma unroll
        for (int p = 0; p < 2; ++p)
            #pragma unroll
            for (int gi = 0; gi < 16; ++gi)
                mx[p][gi] = fmaxf(mx[p][gi], __shfl_xor(mx[p][gi], off, 64));
    if (nl == 0) {
        #pragma unroll
        for (int p = 0; p < 2; ++p)
            #pragma unroll
            for (int gi = 0; gi < 16; ++gi) {
                int row = (gi & 3) + 8 * (gi >> 2) + 4 * kh;
                mred[(p * 32 + row) * 4 + w] = mx[p][gi];
            }
    }
    __syncthreads();
    if (tid < 64)
        mg[tid] = fmaxf(fmaxf(mred[tid * 4], mred[tid * 4 + 1]),
                        fmaxf(mred[tid * 4 + 2], mred[tid * 4 + 3]));
    __syncthreads();
    float sp[2][16], dp[2][16];
    #pragma unroll
    for (int p = 0; p < 2; ++p)
        #pragma unroll
        for (int gi = 0; gi < 16; ++gi) {
            int row = (gi & 3) + 8 * (gi >> 2) + 4 * kh;
            float m  = mg[p * 32 + row];
            float e0 = __expf(acc[p][0][gi] - m);
            float e1 = __expf(acc[p][1][gi] - m);
            sp[p][gi] = e0 + e1;
            dp[p][gi] = e0 * acc[p + 2][0][gi] + e1 * acc[p + 2][1][gi];
        }
    #pragma unroll
    for (int off = 1; off <= 16; off <<= 1)
        #pragma unroll
        for (int p = 0; p < 2; ++p)
            #pragma unroll
            for (int gi = 0; gi < 16; ++gi) {
                sp[p][gi] += __shfl_xor(sp[p][gi], off, 64);
                dp[p][gi] += __shfl_xor(dp[p][gi], off, 64);
            }
    if (nl == 0) {
        #pragma unroll
        for (int p = 0; p < 2; ++p)
            #pragma unroll
            for (int gi = 0; gi < 16; ++gi) {
                int row = (gi & 3) + 8 * (gi >> 2) + 4 * kh;
                sred[(p * 32 + row) * 4 + w] = sp[p][gi];
                dred[(p * 32 + row) * 4 + w] = dp[p][gi];
            }
    }
    __syncthreads();
    if (tid < 64) {
        float s = sred[tid * 4] + sred[tid * 4 + 1] + sred[tid * 4 + 2] + sred[tid * 4 + 3];
        float d = dred[tid * 4] + dred[tid * 4 + 1] + dred[tid * 4 + 2] + dred[tid * 4 + 3];
        int ig = t2 * 64 + tid;
        if (ig < NA) out[b * NA + ig] = d / s;
    }
}

// ---- launcher ----
extern "C" void kernel_launch(void* const* d_in, const int* in_sizes, int n_in,
                              void* d_out, int out_size, void* d_ws, size_t ws_size,
                              hipStream_t stream) {
    const float* img = (const float*)d_in[0];
    const float* V   = (const float*)d_in[1];
    const float* W1  = (const float*)d_in[2];
    const float* W2  = (const float*)d_in[3];
    float* out = (float*)d_out;

    char* ws = (char*)d_ws;
    size_t off = 0;
    float*    invg = (float*)(ws + off);    off += (size_t)NB * RR * 4;
    _Float16* avT  = (_Float16*)(ws + off); off += (size_t)NB * CF * RR * 2;
    _Float16* Qb   = (_Float16*)(ws + off); off += (size_t)NKC * MT * 32 * 2;

    k_prep<<<dim3(4, NB), 256, 0, stream>>>(img, invg, avT);
    k_q<<<dim3(160, 4), 256, 0, stream>>>(V, W1, W2, Qb);
    k_gemm<<<dim3(640), 256, 0, stream>>>(Qb, avT, invg, out);
}